// Round 2
// baseline (607.474 us; speedup 1.0000x reference)
//
#include <hip/hip_runtime.h>

// SpectralClassifier: the DCT-II -> bandpass(k in [0,15)) -> IDCT -> mean(m)
// chain collapses analytically: sum_m IDCT-basis(m,k) == 0 for all k>=1
// (sum_{m=0}^{N-1} cos((2m+1)pi k/2N) = sin(pi k)/(2 sin(pi k/2N)) = 0), so
// only the k=0 (DC) term survives:
//   v[b,d] = (1/127) * sum_{s=1..127} mask[b,s] * hidden[b,s,d]
// followed by the 768->256->64->2 ReLU MLP (all biases zero in setup, but we
// still apply them).

#define BB   1024
#define SS   128
#define DD   768
#define VEC4 (DD / 4)   // 192 float4 per row

// ---------------- Kernel 1: masked row-sum over seq (HBM-bound) ------------
// One block per batch. 192 threads, one float4 column each.
// Active seq positions are compacted into LDS first so the inner loop is
// branch-free and skips masked-out rows entirely (halves HBM traffic for a
// ~50%-dense mask).
//
// Mask dtype: harness marshals bool as int32 ("integer -> const int*"), but
// we probe at runtime to be safe: if the first 512 bytes look like int32
// {0,1} (all bytes at offset % 4 != 0 are zero), treat as int32, else uint8.
__global__ __launch_bounds__(192) void spectral_reduce_kernel(
    const float* __restrict__ hidden,        // [B,S,D]
    const unsigned char* __restrict__ mask8, // [B,S] bool: int32 or uint8
    float* __restrict__ v)                   // [B,D]
{
    const int b = blockIdx.x;
    const int t = threadIdx.x;  // 0..191

    __shared__ int slist[SS];
    __shared__ int scount;
    __shared__ int is_i32;
    if (t == 0) {
        scount = 0;
        int f = 1;
        // probe first 128 putative int32 elements (512 bytes, L2-hot)
        for (int j = 0; j < 128; ++j) {
            if (mask8[4 * j + 1] | mask8[4 * j + 2] | mask8[4 * j + 3]) { f = 0; break; }
        }
        is_i32 = f;
    }
    __syncthreads();

    const int as_i32 = is_i32;
    // positions 1..127 (CLS at s=0 is dropped by the reference)
    if (t < SS - 1) {
        int s = t + 1;
        size_t idx = (size_t)b * SS + s;
        int mv = as_i32 ? (((const int*)mask8)[idx] != 0) : (mask8[idx] != 0);
        if (mv) {
            int p = atomicAdd(&scount, 1);
            slist[p] = s;
        }
    }
    __syncthreads();

    const int n = scount;
    const float4* hp = (const float4*)(hidden + (size_t)b * SS * DD);

    float4 acc = make_float4(0.f, 0.f, 0.f, 0.f);
    int i = 0;
    // unroll-by-4 for outstanding-load ILP
    for (; i + 3 < n; i += 4) {
        float4 x0 = hp[slist[i + 0] * VEC4 + t];
        float4 x1 = hp[slist[i + 1] * VEC4 + t];
        float4 x2 = hp[slist[i + 2] * VEC4 + t];
        float4 x3 = hp[slist[i + 3] * VEC4 + t];
        acc.x += x0.x; acc.y += x0.y; acc.z += x0.z; acc.w += x0.w;
        acc.x += x1.x; acc.y += x1.y; acc.z += x1.z; acc.w += x1.w;
        acc.x += x2.x; acc.y += x2.y; acc.z += x2.z; acc.w += x2.w;
        acc.x += x3.x; acc.y += x3.y; acc.z += x3.z; acc.w += x3.w;
    }
    for (; i < n; ++i) {
        float4 x = hp[slist[i] * VEC4 + t];
        acc.x += x.x; acc.y += x.y; acc.z += x.z; acc.w += x.w;
    }

    const float sc = 1.0f / 127.0f;
    float4 r = make_float4(acc.x * sc, acc.y * sc, acc.z * sc, acc.w * sc);
    ((float4*)(v + (size_t)b * DD))[t] = r;
}

// ---------------- Kernel 2: fused 3-layer MLP ------------------------------
// BM=4 batch rows per block, 256 threads. W1 (786 KB) stays L2/L3-resident.
#define BM 4
__global__ __launch_bounds__(256) void spectral_mlp_kernel(
    const float* __restrict__ v,   // [B,D]
    const float* __restrict__ W1, const float* __restrict__ b1,  // [768,256],[256]
    const float* __restrict__ W2, const float* __restrict__ b2,  // [256,64],[64]
    const float* __restrict__ W3, const float* __restrict__ b3,  // [64,2],[2]
    float* __restrict__ out)       // [B,2]
{
    __shared__ float vs[BM * DD];     // 12 KB
    __shared__ float h1[BM][256];     // 4 KB
    __shared__ float h2[BM][64];      // 1 KB

    const int t  = threadIdx.x;
    const int b0 = blockIdx.x * BM;

    // stage v rows
    for (int i = t; i < BM * DD; i += 256)
        vs[i] = v[(size_t)b0 * DD + i];
    __syncthreads();

    // ---- layer 1: each thread owns output column j = t for all 4 rows ----
    {
        float a0 = b1[t], a1 = a0, a2 = a0, a3 = a0;
        const float* vr0 = vs;
        const float* vr1 = vs + DD;
        const float* vr2 = vs + 2 * DD;
        const float* vr3 = vs + 3 * DD;
        #pragma unroll 4
        for (int i = 0; i < DD; ++i) {
            float w = W1[i * 256 + t];   // coalesced: 1 KB per i across block
            a0 = fmaf(vr0[i], w, a0);
            a1 = fmaf(vr1[i], w, a1);
            a2 = fmaf(vr2[i], w, a2);
            a3 = fmaf(vr3[i], w, a3);
        }
        h1[0][t] = fmaxf(a0, 0.f);
        h1[1][t] = fmaxf(a1, 0.f);
        h1[2][t] = fmaxf(a2, 0.f);
        h1[3][t] = fmaxf(a3, 0.f);
    }
    __syncthreads();

    // ---- layer 2: 4 rows x 64 cols = 256 outputs, one per thread ----
    {
        const int r = t >> 6;      // wave-uniform (64-lane waves)
        const int j = t & 63;
        float a = b2[j];
        #pragma unroll 4
        for (int i = 0; i < 256; ++i)
            a = fmaf(h1[r][i], W2[i * 64 + j], a);
        h2[r][j] = fmaxf(a, 0.f);
    }
    __syncthreads();

    // ---- layer 3: 4 rows x 2 logits ----
    if (t < BM * 2) {
        const int r = t >> 1;
        const int c = t & 1;
        float a = b3[c];
        #pragma unroll
        for (int i = 0; i < 64; ++i)
            a = fmaf(h2[r][i], W3[i * 2 + c], a);
        out[(size_t)(b0 + r) * 2 + c] = a;
    }
}

extern "C" void kernel_launch(void* const* d_in, const int* in_sizes, int n_in,
                              void* d_out, int out_size, void* d_ws, size_t ws_size,
                              hipStream_t stream) {
    const float*         hidden = (const float*)d_in[0];
    const unsigned char* mask   = (const unsigned char*)d_in[1];  // dtype probed in-kernel
    const float*         W1     = (const float*)d_in[2];
    const float*         b1     = (const float*)d_in[3];
    const float*         W2     = (const float*)d_in[4];
    const float*         b2     = (const float*)d_in[5];
    const float*         W3     = (const float*)d_in[6];
    const float*         b3     = (const float*)d_in[7];
    float*               out    = (float*)d_out;

    float* v = (float*)d_ws;  // [B, D] = 3 MB scratch

    spectral_reduce_kernel<<<BB, 192, 0, stream>>>(hidden, mask, v);
    spectral_mlp_kernel<<<BB / BM, 256, 0, stream>>>(v, W1, b1, W2, b2, W3, b3, out);
}

// Round 4
// 536.601 us; speedup vs baseline: 1.1321x; 1.1321x over previous
//
#include <hip/hip_runtime.h>

// SpectralClassifier: the DCT-II -> bandpass(k in [0,15)) -> IDCT -> mean(m)
// chain collapses analytically: sum_m IDCT-basis(m,k) == 0 for all k>=1
// (sum_{m=0}^{N-1} cos((2m+1)pi k/2N) = sin(pi k)/(2 sin(pi k/2N)) = 0), so
// only the k=0 (DC) term survives:
//   v[b,d] = (1/127) * sum_{s=1..127} mask[b,s] * hidden[b,s,d]
// followed by the 768->256->64->2 ReLU MLP.
//
// NOTE on dur_us: harness reset traffic (1.5 GiB 0xAA poison fill ~248 us +
// 402 MB hidden restore ~130 us) dominates the reported duration; the two
// kernels below are a ~50 us slice. Optimizations target that slice.

#define BB   1024
#define SS   128
#define DD   768
#define VEC4 (DD / 4)   // 192 float4 per row

// native clang vector type: required by __builtin_nontemporal_load
// (HIP's float4 is a struct and is rejected by the builtin)
typedef float floatx4 __attribute__((ext_vector_type(4)));

// ---------------- Kernel 1: masked row-sum over seq (HBM-bound) ------------
// One block per batch, 192 threads = one float4 column each. Active seq
// positions are compacted (as precomputed float4 offsets) into LDS so the
// inner loop is branch-free and masked-out rows are never fetched.
//
// Mask dtype: bool is marshaled as int32 by the harness; a cheap PARALLEL
// probe (128 threads, one putative int32 element each) keeps us robust to
// uint8 marshaling without serial-loop latency.
__global__ __launch_bounds__(192) void spectral_reduce_kernel(
    const float* __restrict__ hidden,        // [B,S,D]
    const unsigned char* __restrict__ mask8, // [B,S] bool: int32 or uint8
    float* __restrict__ v)                   // [B,D]
{
    const int b = blockIdx.x;
    const int t = threadIdx.x;  // 0..191

    __shared__ int slist[SS];
    __shared__ int scount;
    __shared__ int not_i32;
    if (t == 0) { scount = 0; not_i32 = 0; }
    __syncthreads();

    if (t < 128) {
        // bytes 1..3 of putative int32 element t: nonzero => not int32 {0,1}
        const unsigned char* p = mask8 + 4 * t;
        if (p[1] | p[2] | p[3]) not_i32 = 1;   // benign race, same value
    }
    __syncthreads();

    const int as_i32 = !not_i32;
    // positions 1..127 (CLS at s=0 is dropped by the reference)
    if (t >= 1 && t < SS) {
        size_t idx = (size_t)b * SS + t;
        int mv = as_i32 ? (((const int*)mask8)[idx] != 0) : (mask8[idx] != 0);
        if (mv) {
            int p = atomicAdd(&scount, 1);
            slist[p] = t * VEC4;               // precomputed float4 offset
        }
    }
    __syncthreads();

    const int n = scount;
    const floatx4* hp = (const floatx4*)(hidden + (size_t)b * SS * DD);

    // hidden is streamed exactly once -> nontemporal, keep L2/L3 for weights
    floatx4 a0 = (floatx4)0.f;
    floatx4 a1 = (floatx4)0.f;
    int i = 0;
    for (; i + 7 < n; i += 8) {                // 8 loads in flight per lane
        floatx4 x0 = __builtin_nontemporal_load(&hp[slist[i + 0] + t]);
        floatx4 x1 = __builtin_nontemporal_load(&hp[slist[i + 1] + t]);
        floatx4 x2 = __builtin_nontemporal_load(&hp[slist[i + 2] + t]);
        floatx4 x3 = __builtin_nontemporal_load(&hp[slist[i + 3] + t]);
        floatx4 x4 = __builtin_nontemporal_load(&hp[slist[i + 4] + t]);
        floatx4 x5 = __builtin_nontemporal_load(&hp[slist[i + 5] + t]);
        floatx4 x6 = __builtin_nontemporal_load(&hp[slist[i + 6] + t]);
        floatx4 x7 = __builtin_nontemporal_load(&hp[slist[i + 7] + t]);
        a0 += x0; a1 += x1; a0 += x2; a1 += x3;
        a0 += x4; a1 += x5; a0 += x6; a1 += x7;
    }
    for (; i < n; ++i) {
        a0 += __builtin_nontemporal_load(&hp[slist[i] + t]);
    }
    a0 += a1;

    const float sc = 1.0f / 127.0f;
    floatx4 r = a0 * sc;
    ((floatx4*)(v + (size_t)b * DD))[t] = r;   // cached: kernel 2 re-reads it
}

// ---------------- Kernel 2: fused 3-layer MLP ------------------------------
// BM=4 batch rows per block, 256 threads, 256 blocks (1/CU). W1 (768 KB)
// is read once per block from L2/L3 (201 MB aggregate @ ~34 TB/s ~ 6 us).
#define BM 4
__global__ __launch_bounds__(256) void spectral_mlp_kernel(
    const float* __restrict__ v,   // [B,D]
    const float* __restrict__ W1, const float* __restrict__ b1,  // [768,256],[256]
    const float* __restrict__ W2, const float* __restrict__ b2,  // [256,64],[64]
    const float* __restrict__ W3, const float* __restrict__ b3,  // [64,2],[2]
    float* __restrict__ out)       // [B,2]
{
    __shared__ float vs[BM * DD];     // 12 KB
    __shared__ float h1[BM][256];     // 4 KB
    __shared__ float h2[BM][64];      // 1 KB

    const int t  = threadIdx.x;
    const int b0 = blockIdx.x * BM;

    for (int i = t; i < BM * DD; i += 256)
        vs[i] = v[(size_t)b0 * DD + i];
    __syncthreads();

    // ---- layer 1: thread owns output column j = t for all 4 rows ----
    {
        float a0 = b1[t], a1 = a0, a2 = a0, a3 = a0;
        const float* vr0 = vs;
        const float* vr1 = vs + DD;
        const float* vr2 = vs + 2 * DD;
        const float* vr3 = vs + 3 * DD;
        #pragma unroll 8
        for (int i = 0; i < DD; ++i) {
            float w = W1[i * 256 + t];   // coalesced 1 KB / iteration / block
            a0 = fmaf(vr0[i], w, a0);    // vs reads are LDS broadcast (free)
            a1 = fmaf(vr1[i], w, a1);
            a2 = fmaf(vr2[i], w, a2);
            a3 = fmaf(vr3[i], w, a3);
        }
        h1[0][t] = fmaxf(a0, 0.f);
        h1[1][t] = fmaxf(a1, 0.f);
        h1[2][t] = fmaxf(a2, 0.f);
        h1[3][t] = fmaxf(a3, 0.f);
    }
    __syncthreads();

    // ---- layer 2: 4 rows x 64 cols = 256 outputs, one per thread ----
    {
        const int r = t >> 6;      // wave-uniform (64-lane waves)
        const int j = t & 63;
        float a = b2[j];
        #pragma unroll 8
        for (int i = 0; i < 256; ++i)
            a = fmaf(h1[r][i], W2[i * 64 + j], a);
        h2[r][j] = fmaxf(a, 0.f);
    }
    __syncthreads();

    // ---- layer 3: 4 rows x 2 logits ----
    if (t < BM * 2) {
        const int r = t >> 1;
        const int c = t & 1;
        float a = b3[c];
        #pragma unroll
        for (int i = 0; i < 64; ++i)
            a = fmaf(h2[r][i], W3[i * 2 + c], a);
        out[(size_t)(b0 + r) * 2 + c] = a;
    }
}

extern "C" void kernel_launch(void* const* d_in, const int* in_sizes, int n_in,
                              void* d_out, int out_size, void* d_ws, size_t ws_size,
                              hipStream_t stream) {
    const float*         hidden = (const float*)d_in[0];
    const unsigned char* mask   = (const unsigned char*)d_in[1];  // dtype probed in-kernel
    const float*         W1     = (const float*)d_in[2];
    const float*         b1     = (const float*)d_in[3];
    const float*         W2     = (const float*)d_in[4];
    const float*         b2     = (const float*)d_in[5];
    const float*         W3     = (const float*)d_in[6];
    const float*         b3     = (const float*)d_in[7];
    float*               out    = (float*)d_out;

    float* v = (float*)d_ws;  // [B, D] = 3 MB scratch

    spectral_reduce_kernel<<<BB, 192, 0, stream>>>(hidden, mask, v);
    spectral_mlp_kernel<<<BB / BM, 256, 0, stream>>>(v, W1, b1, W2, b2, W3, b3, out);
}

// Round 5
// 511.972 us; speedup vs baseline: 1.1865x; 1.0481x over previous
//
#include <hip/hip_runtime.h>

// SpectralClassifier: the DCT-II -> bandpass(k in [0,15)) -> IDCT -> mean(m)
// chain collapses analytically: sum_m IDCT-basis(m,k) == 0 for all k>=1
// (sum_{m=0}^{N-1} cos((2m+1)pi k/2N) = sin(pi k)/(2 sin(pi k/2N)) = 0), so
// only the k=0 (DC) term survives:
//   v[b,d] = (1/127) * sum_{s=1..127} mask[b,s] * hidden[b,s,d]
// followed by the 768->256->64->2 ReLU MLP.
//
// NOTE on dur_us: harness reset traffic (1.5 GiB 0xAA poison fill ~248 us +
// 402 MB hidden restore ~125 us) dominates the reported duration; the two
// kernels below are a ~45-90 us slice. Optimizations target that slice.

#define BB   1024
#define SS   128
#define DD   768
#define VEC4 (DD / 4)   // 192 float4 per row

// native clang vector type: required by __builtin_nontemporal_load
// (HIP's float4 is a struct and is rejected by the builtin)
typedef float floatx4 __attribute__((ext_vector_type(4)));

// ---------------- Kernel 1: masked row-sum over seq (HBM-bound) ------------
// One block per batch, 192 threads = one float4 column each. Active seq
// positions are compacted (as precomputed float4 offsets) into LDS so the
// inner loop is branch-free and masked-out rows are never fetched
// (~201 MB instead of 402 MB for the ~50%-dense mask).
//
// Mask dtype: bool is marshaled as int32 by the harness; a cheap PARALLEL
// probe (128 threads, one putative int32 element each) keeps us robust to
// uint8 marshaling without serial-loop latency.
__global__ __launch_bounds__(192) void spectral_reduce_kernel(
    const float* __restrict__ hidden,        // [B,S,D]
    const unsigned char* __restrict__ mask8, // [B,S] bool: int32 or uint8
    float* __restrict__ v)                   // [B,D]
{
    const int b = blockIdx.x;
    const int t = threadIdx.x;  // 0..191

    __shared__ int slist[SS];
    __shared__ int scount;
    __shared__ int not_i32;
    if (t == 0) { scount = 0; not_i32 = 0; }
    __syncthreads();

    if (t < 128) {
        // bytes 1..3 of putative int32 element t: nonzero => not int32 {0,1}
        const unsigned char* p = mask8 + 4 * t;
        if (p[1] | p[2] | p[3]) not_i32 = 1;   // benign race, same value
    }
    __syncthreads();

    const int as_i32 = !not_i32;
    // positions 1..127 (CLS at s=0 is dropped by the reference)
    if (t >= 1 && t < SS) {
        size_t idx = (size_t)b * SS + t;
        int mv = as_i32 ? (((const int*)mask8)[idx] != 0) : (mask8[idx] != 0);
        if (mv) {
            int p = atomicAdd(&scount, 1);
            slist[p] = t * VEC4;               // precomputed float4 offset
        }
    }
    __syncthreads();

    const int n = scount;
    const floatx4* hp = (const floatx4*)(hidden + (size_t)b * SS * DD);

    // hidden is streamed exactly once -> nontemporal, keep L2/L3 for weights
    floatx4 a0 = (floatx4)0.f;
    floatx4 a1 = (floatx4)0.f;
    int i = 0;
    for (; i + 7 < n; i += 8) {                // 8 loads in flight per lane
        floatx4 x0 = __builtin_nontemporal_load(&hp[slist[i + 0] + t]);
        floatx4 x1 = __builtin_nontemporal_load(&hp[slist[i + 1] + t]);
        floatx4 x2 = __builtin_nontemporal_load(&hp[slist[i + 2] + t]);
        floatx4 x3 = __builtin_nontemporal_load(&hp[slist[i + 3] + t]);
        floatx4 x4 = __builtin_nontemporal_load(&hp[slist[i + 4] + t]);
        floatx4 x5 = __builtin_nontemporal_load(&hp[slist[i + 5] + t]);
        floatx4 x6 = __builtin_nontemporal_load(&hp[slist[i + 6] + t]);
        floatx4 x7 = __builtin_nontemporal_load(&hp[slist[i + 7] + t]);
        a0 += x0; a1 += x1; a0 += x2; a1 += x3;
        a0 += x4; a1 += x5; a0 += x6; a1 += x7;
    }
    for (; i < n; ++i) {
        a0 += __builtin_nontemporal_load(&hp[slist[i] + t]);
    }
    a0 += a1;

    const float sc = 1.0f / 127.0f;
    floatx4 r = a0 * sc;
    ((floatx4*)(v + (size_t)b * DD))[t] = r;   // cached: kernel 2 re-reads it
}

// ---------------- Kernel 2: fused 3-layer MLP ------------------------------
// BM=4 batch rows per block, 256 threads, 256 blocks (1/CU). W1 (768 KB)
// is read once per block from L2/L3 (197 MB aggregate @ ~34 TB/s ~ 6 us).
// All LDS activation reads are wave-uniform broadcasts done as b128
// (one ds_read_b128 ~12 cyc replaces four ds_read_b32 ~23 cyc).
#define BM 4
__global__ __launch_bounds__(256) void spectral_mlp_kernel(
    const float* __restrict__ v,   // [B,D]
    const float* __restrict__ W1, const float* __restrict__ b1,  // [768,256],[256]
    const float* __restrict__ W2, const float* __restrict__ b2,  // [256,64],[64]
    const float* __restrict__ W3, const float* __restrict__ b3,  // [64,2],[2]
    float* __restrict__ out)       // [B,2]
{
    __shared__ float vs[BM * DD];     // 12 KB
    __shared__ float h1[BM][256];     // 4 KB
    __shared__ float h2[BM][64];      // 1 KB

    const int t  = threadIdx.x;
    const int b0 = blockIdx.x * BM;

    // stage v rows, vectorized: 768 float4 over 256 threads (3 each)
    {
        const floatx4* src = (const floatx4*)(v + (size_t)b0 * DD);
        floatx4* dst = (floatx4*)vs;
        #pragma unroll
        for (int i = t; i < BM * VEC4; i += 256)
            dst[i] = src[i];
    }
    __syncthreads();

    // ---- layer 1: thread owns output column j = t for all 4 rows ----
    {
        float a0 = b1[t], a1 = a0, a2 = a0, a3 = a0;
        const floatx4* vr0 = (const floatx4*)vs;
        const floatx4* vr1 = (const floatx4*)(vs + DD);
        const floatx4* vr2 = (const floatx4*)(vs + 2 * DD);
        const floatx4* vr3 = (const floatx4*)(vs + 3 * DD);
        #pragma unroll 4
        for (int i4 = 0; i4 < VEC4; ++i4) {     // 192 groups of 4 k-steps
            floatx4 x0 = vr0[i4];               // ds_read_b128, broadcast
            floatx4 x1 = vr1[i4];
            floatx4 x2 = vr2[i4];
            floatx4 x3 = vr3[i4];
            float w0 = W1[(4 * i4 + 0) * 256 + t];  // coalesced 1 KB/step
            float w1 = W1[(4 * i4 + 1) * 256 + t];
            float w2 = W1[(4 * i4 + 2) * 256 + t];
            float w3 = W1[(4 * i4 + 3) * 256 + t];
            a0 = fmaf(x0.x, w0, a0); a0 = fmaf(x0.y, w1, a0);
            a0 = fmaf(x0.z, w2, a0); a0 = fmaf(x0.w, w3, a0);
            a1 = fmaf(x1.x, w0, a1); a1 = fmaf(x1.y, w1, a1);
            a1 = fmaf(x1.z, w2, a1); a1 = fmaf(x1.w, w3, a1);
            a2 = fmaf(x2.x, w0, a2); a2 = fmaf(x2.y, w1, a2);
            a2 = fmaf(x2.z, w2, a2); a2 = fmaf(x2.w, w3, a2);
            a3 = fmaf(x3.x, w0, a3); a3 = fmaf(x3.y, w1, a3);
            a3 = fmaf(x3.z, w2, a3); a3 = fmaf(x3.w, w3, a3);
        }
        h1[0][t] = fmaxf(a0, 0.f);
        h1[1][t] = fmaxf(a1, 0.f);
        h1[2][t] = fmaxf(a2, 0.f);
        h1[3][t] = fmaxf(a3, 0.f);
    }
    __syncthreads();

    // ---- layer 2: 4 rows x 64 cols = 256 outputs, one per thread ----
    {
        const int r = t >> 6;      // wave-uniform (64-lane waves)
        const int j = t & 63;
        float a = b2[j];
        const floatx4* hr = (const floatx4*)h1[r];  // 1 KB-aligned
        #pragma unroll 4
        for (int i4 = 0; i4 < 64; ++i4) {
            floatx4 x = hr[i4];                 // ds_read_b128, broadcast
            a = fmaf(x.x, W2[(4 * i4 + 0) * 64 + j], a);
            a = fmaf(x.y, W2[(4 * i4 + 1) * 64 + j], a);
            a = fmaf(x.z, W2[(4 * i4 + 2) * 64 + j], a);
            a = fmaf(x.w, W2[(4 * i4 + 3) * 64 + j], a);
        }
        h2[r][j] = fmaxf(a, 0.f);
    }
    __syncthreads();

    // ---- layer 3: 4 rows x 2 logits ----
    if (t < BM * 2) {
        const int r = t >> 1;
        const int c = t & 1;
        float a = b3[c];
        const floatx4* hr = (const floatx4*)h2[r];
        #pragma unroll
        for (int i4 = 0; i4 < 16; ++i4) {
            floatx4 x = hr[i4];
            a = fmaf(x.x, W3[(4 * i4 + 0) * 2 + c], a);
            a = fmaf(x.y, W3[(4 * i4 + 1) * 2 + c], a);
            a = fmaf(x.z, W3[(4 * i4 + 2) * 2 + c], a);
            a = fmaf(x.w, W3[(4 * i4 + 3) * 2 + c], a);
        }
        out[(size_t)(b0 + r) * 2 + c] = a;
    }
}

extern "C" void kernel_launch(void* const* d_in, const int* in_sizes, int n_in,
                              void* d_out, int out_size, void* d_ws, size_t ws_size,
                              hipStream_t stream) {
    const float*         hidden = (const float*)d_in[0];
    const unsigned char* mask   = (const unsigned char*)d_in[1];  // dtype probed in-kernel
    const float*         W1     = (const float*)d_in[2];
    const float*         b1     = (const float*)d_in[3];
    const float*         W2     = (const float*)d_in[4];
    const float*         b2     = (const float*)d_in[5];
    const float*         W3     = (const float*)d_in[6];
    const float*         b3     = (const float*)d_in[7];
    float*               out    = (float*)d_out;

    float* v = (float*)d_ws;  // [B, D] = 3 MB scratch

    spectral_reduce_kernel<<<BB, 192, 0, stream>>>(hidden, mask, v);
    spectral_mlp_kernel<<<BB / BM, 256, 0, stream>>>(v, W1, b1, W2, b2, W3, b3, out);
}